// Round 18
// baseline (290.455 us; speedup 1.0000x reference)
//
#include <hip/hip_runtime.h>
#include <hip/hip_fp16.h>

// Problem constants (fixed by the reference)
#define N_NODES   50000
#define N_EDGES   800000
#define IN_DIM    128
#define HID       64
#define OUT_DIM   128
#define N_GRAPHS  128

#define NBKT      196        // ceil(50000/256) coarse dst-buckets
#define BBLK2     784        // bucket blocks, 1024 edges each (784*1024 >= 800000)
#define SLICE     36         // private slot count per (bucket, block); lambda=5.2
#define BSTRIDE   5120       // max edges per bucket (16-sigma margin, lambda=4082)

// Workspace layout in 4-byte words.
#define OFF_GSTART 0                     // int[130]
#define OFF_ROWPTR 130                   // int[50001]
#define OFF_SRCL   50132                 // ushort[800000] = 400000 words
#define OFF_COUNTS 450132                // ushort[196*784] = 76832 words
#define OFF_EPAIRS 526964                // uint[196*784*36] = 5,531,904 words (16B-aligned)
#define OFF_HA     6058868               // fp8[50000*64] = 800,000 words (8B-aligned)
#define OFF_HB     6858868               // fp8[50000*64] = 800,000 words
// end = 7,658,868 words = 30.6 MB

// ---------------------------------------------------------------- fp8 helpers (HW cvt, e4m3 on gfx950)
typedef float v2f __attribute__((ext_vector_type(2)));

__device__ __forceinline__ void acc_fp8x8(float acc[8], const uint2 w) {
    const v2f a = __builtin_amdgcn_cvt_pk_f32_fp8(w.x, false);
    const v2f b = __builtin_amdgcn_cvt_pk_f32_fp8(w.x, true);
    const v2f c = __builtin_amdgcn_cvt_pk_f32_fp8(w.y, false);
    const v2f d = __builtin_amdgcn_cvt_pk_f32_fp8(w.y, true);
    acc[0] += a.x; acc[1] += a.y; acc[2] += b.x; acc[3] += b.y;
    acc[4] += c.x; acc[5] += c.y; acc[6] += d.x; acc[7] += d.y;
}

__device__ __forceinline__ uint2 pack_fp8x8(const float f[8]) {
    int w0 = 0, w1 = 0;
    w0 = __builtin_amdgcn_cvt_pk_fp8_f32(f[0], f[1], w0, false);
    w0 = __builtin_amdgcn_cvt_pk_fp8_f32(f[2], f[3], w0, true);
    w1 = __builtin_amdgcn_cvt_pk_fp8_f32(f[4], f[5], w1, false);
    w1 = __builtin_amdgcn_cvt_pk_fp8_f32(f[6], f[7], w1, true);
    uint2 r; r.x = (unsigned)w0; r.y = (unsigned)w1;
    return r;
}

// ================================================================ K1: bucket scatter (atomic-free) + gbound
// blocks [0,BBLK2): bucket block w owns 1024 edges; LDS-only bucketing, then
// writes private slice epairs[(b*BBLK2+w)*SLICE ...] + counts[b*BBLK2+w].
// blocks [BBLK2, BBLK2+NBKT): graph boundaries.
#define BG_SMEM_BYTES (800 + NBKT * SLICE * 4)   // lcnt(196,pad 200w) + stage = 29024

__device__ __forceinline__ void role_bucket(char* smem, const int* __restrict__ ei,
                                            unsigned short* __restrict__ counts,
                                            unsigned int* __restrict__ epairs,
                                            int bid) {
    int* lcnt = (int*)smem;                                   // 196 (padded 200)
    unsigned int* stage = (unsigned int*)(smem + 800);        // 196*SLICE, 16B-aligned
    const int t = threadIdx.x;
    for (int i = t; i < NBKT; i += 256) lcnt[i] = 0;
    __syncthreads();
    const int e0 = bid * 1024;
#pragma unroll
    for (int k = 0; k < 4; ++k) {
        const int e = e0 + k * 256 + t;
        if (e < N_EDGES) {
            const unsigned int src = (unsigned int)ei[e];
            const unsigned int dst = (unsigned int)ei[N_EDGES + e];
            const int b = dst >> 8;
            const unsigned int pk = src | (dst << 16);        // both < 2^16
            const int pos = atomicAdd(&lcnt[b], 1);           // LDS atomic only
            if (pos < SLICE) stage[b * SLICE + pos] = pk;     // overflow: e^-35, never
        }
    }
    __syncthreads();
    if (t < NBKT) {
        int n = lcnt[t]; if (n > SLICE) n = SLICE;
        counts[t * BBLK2 + bid] = (unsigned short)n;
        unsigned int* dstp = epairs + ((size_t)t * BBLK2 + bid) * SLICE;  // 144B-aligned
        for (int i = 0; i < n; i += 4)                        // SLICE%4==0: safe overwrite
            *(uint4*)&dstp[i] = *(const uint4*)&stage[t * SLICE + i];
    }
}

__device__ __forceinline__ void role_gbound(const int* __restrict__ batch,
                                            int* __restrict__ gstart, int bid) {
    const int n = bid * 256 + threadIdx.x;
    if (n >= N_NODES) return;
    const int b = batch[n];
    if (n == 0) {
        for (int g = 0; g <= b; ++g) gstart[g] = 0;
    } else {
        const int p = batch[n - 1];
        for (int g = p + 1; g <= b; ++g) gstart[g] = n;
    }
    if (n == N_NODES - 1) {
        for (int g = b + 1; g <= N_GRAPHS; ++g) gstart[g] = N_NODES;
    }
}

__global__ __launch_bounds__(256) void k_bg(
        const int* __restrict__ ei, const int* __restrict__ batch,
        unsigned short* __restrict__ counts, unsigned int* __restrict__ epairs,
        int* __restrict__ gstart) {
    __shared__ __attribute__((aligned(16))) char smem[BG_SMEM_BYTES];
    const int bid = blockIdx.x;
    if (bid < BBLK2) role_bucket(smem, ei, counts, epairs, bid);
    else             role_gbound(batch, gstart, bid - BBLK2);
}

// ================================================================ K2: CSR build (atomic-free base) + proj_in
// blocks [0,NBKT): csr; [NBKT,NBKT+782): proj (independent, fills idle CUs).
#define S_X2 132              // fp16 x-tile stride
#define CP_SMEM_BYTES 33280   // proj: 16896 + 16384; csr uses ~14KB

__device__ __forceinline__ void role_csr(char* smem,
                                         const unsigned short* __restrict__ counts,
                                         const unsigned int* __restrict__ epairs,
                                         int* __restrict__ rowptr,
                                         unsigned short* __restrict__ srclist, int b) {
    int* lhist = (int*)smem;                        // 256
    int* lcur  = lhist + 256;                       // 256
    int* pws   = lcur + 256;                        // 4
    int* wtot  = pws + 4;                           // 4
    int* ltot  = wtot + 4;                          // 1 (+3 pad)
    unsigned short* scnt = (unsigned short*)(ltot + 4);   // 784
    unsigned short* lsrc = scnt + BBLK2;            // 5120
    const int t = threadIdx.x;
    const int lane = t & 63, wv = t >> 6;

    // base = total edges in buckets < b  (contiguous counts[0 .. b*784), uint2-packed)
    int po = 0;
    const unsigned int* c32 = (const unsigned int*)counts;
    const int nw = b * (BBLK2 / 2);                 // b*392 uints
    for (int i = t; i < nw; i += 256) {
        const unsigned int v = c32[i];
        po += (int)(v & 0xFFFFu) + (int)(v >> 16);
    }
#pragma unroll
    for (int m = 32; m; m >>= 1) po += __shfl_xor(po, m, 64);
    if (lane == 0) pws[wv] = po;
    // stage this bucket's per-slice counts
    for (int i = t; i < BBLK2; i += 256) scnt[i] = counts[b * BBLK2 + i];
    lhist[t] = 0;
    __syncthreads();
    const int base = pws[0] + pws[1] + pws[2] + pws[3];

    // histogram of fine-dst over all slots of bucket b
    const int TOT = BBLK2 * SLICE;                  // 28224
    const size_t ebase = (size_t)b * BBLK2 * SLICE;
    for (int s = t; s < TOT; s += 256) {
        const int w = s / SLICE, i = s - w * SLICE;
        if (i < (int)scnt[w])
            atomicAdd(&lhist[(epairs[ebase + s] >> 16) & 255], 1);
    }
    __syncthreads();

    // exclusive scan of lhist[256]
    const int d = lhist[t];
    int incl = d;
#pragma unroll
    for (int off = 1; off < 64; off <<= 1) {
        const int u = __shfl_up(incl, off, 64);
        if (lane >= off) incl += u;
    }
    if (lane == 63) wtot[wv] = incl;
    __syncthreads();
    int woff = 0;
#pragma unroll
    for (int i = 0; i < 4; ++i) woff += (i < wv) ? wtot[i] : 0;
    const int excl = woff + incl - d;
    lcur[t] = excl;
    if (t == 255) *ltot = excl + d;                 // bucket total
    const int node = b * 256 + t;
    if (node < N_NODES) rowptr[node] = base + excl;
    __syncthreads();
    const int cnt = *ltot;
    if (b == NBKT - 1 && t == 0) rowptr[N_NODES] = base + cnt;  // == N_EDGES

    // scatter src into fine order (LDS)
    for (int s = t; s < TOT; s += 256) {
        const int w = s / SLICE, i = s - w * SLICE;
        if (i < (int)scnt[w]) {
            const unsigned int u = epairs[ebase + s];
            const int pos = atomicAdd(&lcur[(u >> 16) & 255], 1);
            lsrc[pos] = (unsigned short)(u & 0xFFFFu);
        }
    }
    __syncthreads();
    for (int i = t; i < cnt; i += 256)
        srclist[base + i] = lsrc[i];
}

__device__ __forceinline__ void role_proj(char* smem, const float* __restrict__ x,
                                          const float* __restrict__ W,
                                          const float* __restrict__ b,
                                          unsigned char* __restrict__ h8, int bid) {
    __half* A = (__half*)smem;                    // 64*132 halves = 16896 B
    float* Wl = (float*)(smem + 64 * S_X2 * 2);   // 64*64 floats = 16384 B
    const int t = threadIdx.x;
    const int nb = bid * 64;
    for (int i = t; i < 64 * HID; i += 256) Wl[i] = W[i];   // k = 0..63
    for (int i = t; i < 64 * (IN_DIM / 4); i += 256) {
        const int n = i >> 5;
        const int k4 = (i & 31) * 4;
        float4 val = make_float4(0.f, 0.f, 0.f, 0.f);
        if (nb + n < N_NODES)
            val = *(const float4*)(x + (size_t)(nb + n) * IN_DIM + k4);
        union { uint2 u; __half2 h[2]; } pk;
        pk.h[0] = __floats2half2_rn(val.x, val.y);
        pk.h[1] = __floats2half2_rn(val.z, val.w);
        *(uint2*)&A[n * S_X2 + k4] = pk.u;
    }
    __syncthreads();

    const int ln = t & 31;
    const int c0 = (t >> 5) * 8;
    float acc[2][8];
#pragma unroll
    for (int j = 0; j < 2; ++j)
#pragma unroll
        for (int c = 0; c < 8; ++c) acc[j][c] = b[c0 + c];
    for (int k = 0; k < 64; ++k) {
        const float a0 = __half2float(A[ln * S_X2 + k]);
        const float a1 = __half2float(A[(ln + 32) * S_X2 + k]);
        const float4 wA = *(const float4*)&Wl[k * HID + c0];
        const float4 wB = *(const float4*)&Wl[k * HID + c0 + 4];
        const float w[8] = {wA.x, wA.y, wA.z, wA.w, wB.x, wB.y, wB.z, wB.w};
#pragma unroll
        for (int c = 0; c < 8; ++c) {
            acc[0][c] = fmaf(a0, w[c], acc[0][c]);
            acc[1][c] = fmaf(a1, w[c], acc[1][c]);
        }
    }
    __syncthreads();                                        // Wl half-1 reads done
    for (int i = t; i < 64 * HID; i += 256) Wl[i] = W[64 * HID + i];  // k = 64..127
    __syncthreads();
    for (int k = 64; k < 128; ++k) {
        const float a0 = __half2float(A[ln * S_X2 + k]);
        const float a1 = __half2float(A[(ln + 32) * S_X2 + k]);
        const float4 wA = *(const float4*)&Wl[(k - 64) * HID + c0];
        const float4 wB = *(const float4*)&Wl[(k - 64) * HID + c0 + 4];
        const float w[8] = {wA.x, wA.y, wA.z, wA.w, wB.x, wB.y, wB.z, wB.w};
#pragma unroll
        for (int c = 0; c < 8; ++c) {
            acc[0][c] = fmaf(a0, w[c], acc[0][c]);
            acc[1][c] = fmaf(a1, w[c], acc[1][c]);
        }
    }
#pragma unroll
    for (int j = 0; j < 2; ++j) {
        const int n = nb + ln + 32 * j;
        if (n < N_NODES) {
            const uint2 p = pack_fp8x8(acc[j]);
            *(uint2*)(h8 + (size_t)n * HID + c0) = p;
        }
    }
}

__global__ __launch_bounds__(256) void k_cp(
        const unsigned short* __restrict__ counts,
        const unsigned int* __restrict__ epairs,
        const float* __restrict__ x, const float* __restrict__ W,
        const float* __restrict__ b,
        int* __restrict__ rowptr, unsigned short* __restrict__ srcl,
        unsigned char* __restrict__ h8) {
    __shared__ __attribute__((aligned(16))) char smem[CP_SMEM_BYTES];
    const int bid = blockIdx.x;
    if (bid < NBKT) role_csr(smem, counts, epairs, rowptr, srcl, bid);
    else            role_proj(smem, x, W, b, h8, bid - NBKT);
}

// ---------------------------------------------------------------- fused conv: gather + 2-layer MLP (R16/R17-proven)
#define S_A 65
__global__ __launch_bounds__(256, 4) void k_conv(
        const unsigned char* __restrict__ hin8,
        const int* __restrict__ rowptr, const unsigned short* __restrict__ srclist,
        const float* __restrict__ W1, const float* __restrict__ b1,
        const float* __restrict__ W2, const float* __restrict__ b2,
        unsigned char* __restrict__ hout8) {
    __shared__ float A[64 * S_A];      // 16.6 KB (v, then u)
    __shared__ float Wl[HID * HID];    // 16 KB (W1, then W2)
    const int t = threadIdx.x;
    for (int i = t; i < HID * HID; i += 256) Wl[i] = W1[i];

    const int nb = blockIdx.x * 64;
    const int grp = t >> 3;            // 0..31: node within pass
    const int q = t & 7;               // 8-byte chunk of the 64B row
#pragma unroll
    for (int pass = 0; pass < 2; ++pass) {
        const int nloc = pass * 32 + grp;
        const int node = nb + nloc;
        float acc[8] = {0.f, 0.f, 0.f, 0.f, 0.f, 0.f, 0.f, 0.f};
        if (node < N_NODES) {
            acc_fp8x8(acc, *(const uint2*)(hin8 + (size_t)node * HID + q * 8)); // self
            const int beg = rowptr[node];
            const int end = rowptr[node + 1];
            int e = beg;
            for (; e + 8 <= end; e += 8) {
                int s[8];
#pragma unroll
                for (int i = 0; i < 8; ++i) s[i] = srclist[e + i];
                uint2 r[8];
#pragma unroll
                for (int i = 0; i < 8; ++i)
                    r[i] = *(const uint2*)(hin8 + (size_t)s[i] * HID + q * 8);
#pragma unroll
                for (int i = 0; i < 8; ++i) acc_fp8x8(acc, r[i]);
            }
            for (; e < end; ++e)
                acc_fp8x8(acc, *(const uint2*)(hin8 + (size_t)srclist[e] * HID + q * 8));
        }
        float* dst = &A[nloc * S_A + q * 8];
#pragma unroll
        for (int i = 0; i < 8; ++i) dst[i] = acc[i];
    }
    __syncthreads();

    const int ln = t & 31;
    const int c0 = (t >> 5) * 8;
    float bb[8];
#pragma unroll
    for (int c = 0; c < 8; ++c) bb[c] = b1[c0 + c];

    float acc2[2][8];
    // ---- layer 1
#pragma unroll
    for (int j = 0; j < 2; ++j)
#pragma unroll
        for (int c = 0; c < 8; ++c) acc2[j][c] = bb[c];
    for (int k = 0; k < HID; ++k) {
        const float a0 = A[ln * S_A + k];
        const float a1 = A[(ln + 32) * S_A + k];
        const float4 wA = *(const float4*)&Wl[k * HID + c0];
        const float4 wB = *(const float4*)&Wl[k * HID + c0 + 4];
        const float w[8] = {wA.x, wA.y, wA.z, wA.w, wB.x, wB.y, wB.z, wB.w};
#pragma unroll
        for (int c = 0; c < 8; ++c) {
            acc2[0][c] = fmaf(a0, w[c], acc2[0][c]);
            acc2[1][c] = fmaf(a1, w[c], acc2[1][c]);
        }
    }
    __syncthreads();   // all layer-1 A and Wl reads complete
    // write u = relu(acc2) into A; stage W2 into Wl
#pragma unroll
    for (int j = 0; j < 2; ++j) {
        float* dst = &A[(ln + 32 * j) * S_A + c0];
#pragma unroll
        for (int c = 0; c < 8; ++c) dst[c] = fmaxf(acc2[j][c], 0.0f);
    }
    for (int i = t; i < HID * HID; i += 256) Wl[i] = W2[i];
#pragma unroll
    for (int c = 0; c < 8; ++c) bb[c] = b2[c0 + c];
    __syncthreads();

    // ---- layer 2
#pragma unroll
    for (int j = 0; j < 2; ++j)
#pragma unroll
        for (int c = 0; c < 8; ++c) acc2[j][c] = bb[c];
    for (int k = 0; k < HID; ++k) {
        const float a0 = A[ln * S_A + k];
        const float a1 = A[(ln + 32) * S_A + k];
        const float4 wA = *(const float4*)&Wl[k * HID + c0];
        const float4 wB = *(const float4*)&Wl[k * HID + c0 + 4];
        const float w[8] = {wA.x, wA.y, wA.z, wA.w, wB.x, wB.y, wB.z, wB.w};
#pragma unroll
        for (int c = 0; c < 8; ++c) {
            acc2[0][c] = fmaf(a0, w[c], acc2[0][c]);
            acc2[1][c] = fmaf(a1, w[c], acc2[1][c]);
        }
    }
#pragma unroll
    for (int j = 0; j < 2; ++j) {
        const int n = nb + ln + 32 * j;
        if (n < N_NODES) {
            float f[8];
#pragma unroll
            for (int c = 0; c < 8; ++c) f[c] = fmaxf(acc2[j][c], 0.0f);
            const uint2 p = pack_fp8x8(f);
            *(uint2*)(hout8 + (size_t)n * HID + c0) = p;
        }
    }
}

// ---------------------------------------------------------------- fused mean-pool + proj_out (fp8 read)
__global__ __launch_bounds__(256) void k_poolout(
        const unsigned char* __restrict__ hin8, const int* __restrict__ gstart,
        const float* __restrict__ Wo, const float* __restrict__ bo,
        float* __restrict__ out) {
    __shared__ float Wl[HID * OUT_DIM];   // 32 KB
    __shared__ float red[4][HID];
    __shared__ float mean[HID];
    const int g = blockIdx.x;
    const int t = threadIdx.x;
    for (int i = t; i < HID * OUT_DIM; i += 256) Wl[i] = Wo[i];
    const int c = t & 63;
    const int wv = t >> 6;
    const int beg = gstart[g], end = gstart[g + 1];
    float acc = 0.0f;
    for (int n = beg + wv; n < end; n += 4)
        acc += __builtin_amdgcn_cvt_f32_fp8((int)hin8[(size_t)n * HID + c], 0);
    red[wv][c] = acc;
    __syncthreads();
    if (t < HID) {
        const float cnt = (float)(end - beg);
        mean[t] = cnt > 0.0f ? (red[0][t] + red[1][t] + red[2][t] + red[3][t]) / cnt
                             : 0.0f;
    }
    __syncthreads();
    if (t < OUT_DIM) {
        float o = 0.0f;
        for (int k = 0; k < HID; ++k)
            o = fmaf(mean[k], Wl[k * OUT_DIM + t], o);
        out[g * OUT_DIM + t] = (end > beg) ? o + bo[t] : 0.0f;
    }
}

// ---------------------------------------------------------------- launch
extern "C" void kernel_launch(void* const* d_in, const int* in_sizes, int n_in,
                              void* d_out, int out_size, void* d_ws, size_t ws_size,
                              hipStream_t stream) {
    const float* x     = (const float*)d_in[0];
    const int*   ei    = (const int*)d_in[1];
    const int*   batch = (const int*)d_in[2];
    const float* W_in  = (const float*)d_in[3];
    const float* b_in  = (const float*)d_in[4];
    const float* W1_0  = (const float*)d_in[5];
    const float* b1_0  = (const float*)d_in[6];
    const float* W2_0  = (const float*)d_in[7];
    const float* b2_0  = (const float*)d_in[8];
    const float* W1_1  = (const float*)d_in[9];
    const float* b1_1  = (const float*)d_in[10];
    const float* W2_1  = (const float*)d_in[11];
    const float* b2_1  = (const float*)d_in[12];
    const float* W_out = (const float*)d_in[13];
    const float* b_out = (const float*)d_in[14];
    float* out = (float*)d_out;

    unsigned int*   wsw    = (unsigned int*)d_ws;
    int*            gstart = (int*)(wsw + OFF_GSTART);
    int*            rowptr = (int*)(wsw + OFF_ROWPTR);
    unsigned short* srcl   = (unsigned short*)(wsw + OFF_SRCL);
    unsigned short* counts = (unsigned short*)(wsw + OFF_COUNTS);
    unsigned int*   epairs = (unsigned int*)(wsw + OFF_EPAIRS);
    unsigned char*  hA     = (unsigned char*)(wsw + OFF_HA);
    unsigned char*  hB     = (unsigned char*)(wsw + OFF_HB);

    const int pi_blocks = (N_NODES + 63) / 64;            // 782
    const int cv_blocks = (N_NODES + 63) / 64;            // 782
    const int bg_blocks = BBLK2 + NBKT;                   // 980
    const int cp_blocks = NBKT + pi_blocks;               // 978

    k_bg<<<bg_blocks, 256, 0, stream>>>(ei, batch, counts, epairs, gstart);
    k_cp<<<cp_blocks, 256, 0, stream>>>(counts, epairs, x, W_in, b_in,
                                        rowptr, srcl, hA);
    k_conv<<<cv_blocks, 256, 0, stream>>>(hA, rowptr, srcl, W1_0, b1_0, W2_0, b2_0, hB);
    k_conv<<<cv_blocks, 256, 0, stream>>>(hB, rowptr, srcl, W1_1, b1_1, W2_1, b2_1, hA);
    k_poolout<<<N_GRAPHS, 256, 0, stream>>>(hA, gstart, W_out, b_out, out);
}

// Round 19
// 229.340 us; speedup vs baseline: 1.2665x; 1.2665x over previous
//
#include <hip/hip_runtime.h>
#include <hip/hip_fp16.h>

// Problem constants (fixed by the reference)
#define N_NODES   50000
#define N_EDGES   800000
#define IN_DIM    128
#define HID       64
#define OUT_DIM   128
#define N_GRAPHS  128

#define NBKT      196        // ceil(50000/256) coarse dst-buckets
#define BBLK      784        // bucket-role blocks: <=2 x 512-edge windows each
#define BSTRIDE   5120       // slots/bucket (mean 4096, 16-sigma margin)
#define CAP       40         // LDS staging depth per bucket

// Workspace layout in 4-byte words.
#define OFF_GCUR   0                    // int[196] (zeroed by hipMemsetAsync)
#define OFF_GSTART 196                  // int[130]
#define OFF_ROWPTR 326                  // int[50001]
#define OFF_SRCL   50328                // ushort[800000] = 400000 words
#define OFF_EPAIRS 450328               // uint[196*5120] = 1,003,520 words
#define OFF_HA     1453848              // fp8[50000*64] = 800,000 words (8B-aligned)
#define OFF_HB     2253848              // fp8[50000*64] = 800,000 words
// end = 3,053,848 words = 12.2 MB

// ---------------------------------------------------------------- fp8 helpers (HW cvt, e4m3 on gfx950)
typedef float v2f __attribute__((ext_vector_type(2)));

__device__ __forceinline__ void acc_fp8x8(float acc[8], const uint2 w) {
    const v2f a = __builtin_amdgcn_cvt_pk_f32_fp8(w.x, false);
    const v2f b = __builtin_amdgcn_cvt_pk_f32_fp8(w.x, true);
    const v2f c = __builtin_amdgcn_cvt_pk_f32_fp8(w.y, false);
    const v2f d = __builtin_amdgcn_cvt_pk_f32_fp8(w.y, true);
    acc[0] += a.x; acc[1] += a.y; acc[2] += b.x; acc[3] += b.y;
    acc[4] += c.x; acc[5] += c.y; acc[6] += d.x; acc[7] += d.y;
}

__device__ __forceinline__ uint2 pack_fp8x8(const float f[8]) {
    int w0 = 0, w1 = 0;
    w0 = __builtin_amdgcn_cvt_pk_fp8_f32(f[0], f[1], w0, false);
    w0 = __builtin_amdgcn_cvt_pk_fp8_f32(f[2], f[3], w0, true);
    w1 = __builtin_amdgcn_cvt_pk_fp8_f32(f[4], f[5], w1, false);
    w1 = __builtin_amdgcn_cvt_pk_fp8_f32(f[6], f[7], w1, true);
    uint2 r; r.x = (unsigned)w0; r.y = (unsigned)w1;
    return r;
}

// ================================================================ K1: bucket scatter + graph bounds
// blocks [0,BBLK): bucket (2 windows of 512 edges); [BBLK,BBLK+NBKT): gbound.
#define BG_SMEM_BYTES 32144   // bucket: NBKT*4 + NBKT*CAP*4

__device__ __forceinline__ void role_bucket(char* smem, const int* __restrict__ ei,
                                            int* __restrict__ gcur,
                                            unsigned int* __restrict__ epairs,
                                            int bid) {
    int* lcnt = (int*)smem;                                 // NBKT words
    unsigned int* stage = (unsigned int*)(smem + NBKT * 4); // NBKT*CAP words
    const int t = threadIdx.x;
    for (int i = t; i < NBKT; i += 256) lcnt[i] = 0;
    __syncthreads();
    for (int e0 = bid * 512; e0 < N_EDGES; e0 += BBLK * 512) {
#pragma unroll
        for (int half = 0; half < 2; ++half) {
            const int e = e0 + half * 256 + t;
            if (e < N_EDGES) {
                const unsigned int src = (unsigned int)ei[e];
                const unsigned int dst = (unsigned int)ei[N_EDGES + e];
                const int b = dst >> 8;
                const unsigned int pk = src | (dst << 16);   // both < 2^16
                const int pos = atomicAdd(&lcnt[b], 1);
                if (pos < CAP) stage[b * CAP + pos] = pk;
                else {  // astronomically rare overflow: direct scattered write
                    const int gp = atomicAdd(&gcur[b], 1);
                    epairs[b * BSTRIDE + gp] = pk;
                }
            }
        }
        __syncthreads();
        if (t < NBKT) {
            int n = lcnt[t]; if (n > CAP) n = CAP;
            if (n >= 16) {
                const int f = n & ~15;               // 16 or 32
                const int base = atomicAdd(&gcur[t], f);
                if ((base & 3) == 0) {               // 16B-aligned unless overflow hit
                    for (int i = 0; i < f; i += 4)
                        *(uint4*)&epairs[t * BSTRIDE + base + i] =
                            *(const uint4*)&stage[t * CAP + i];
                } else {                             // scalar fallback
                    for (int i = 0; i < f; ++i)
                        epairs[t * BSTRIDE + base + i] = stage[t * CAP + i];
                }
                for (int i = 0; i < n - f; ++i)      // move remainder to front
                    stage[t * CAP + i] = stage[t * CAP + f + i];
                lcnt[t] = n - f;
            } else {
                lcnt[t] = n;
            }
        }
        __syncthreads();
    }
    // drain remainders (<16 words each; once)
    if (t < NBKT) {
        const int n = lcnt[t];
        if (n > 0) {
            const int base = atomicAdd(&gcur[t], n);
            for (int i = 0; i < n; ++i)
                epairs[t * BSTRIDE + base + i] = stage[t * CAP + i];
        }
    }
}

__device__ __forceinline__ void role_gbound(const int* __restrict__ batch,
                                            int* __restrict__ gstart, int bid) {
    const int n = bid * 256 + threadIdx.x;
    if (n >= N_NODES) return;
    const int b = batch[n];
    if (n == 0) {
        for (int g = 0; g <= b; ++g) gstart[g] = 0;
    } else {
        const int p = batch[n - 1];
        for (int g = p + 1; g <= b; ++g) gstart[g] = n;
    }
    if (n == N_NODES - 1) {
        for (int g = b + 1; g <= N_GRAPHS; ++g) gstart[g] = N_NODES;
    }
}

__global__ __launch_bounds__(256) void k_bg(
        const int* __restrict__ ei, const int* __restrict__ batch,
        int* __restrict__ gcur, unsigned int* __restrict__ epairs,
        int* __restrict__ gstart) {
    __shared__ __attribute__((aligned(16))) char smem[BG_SMEM_BYTES];
    const int bid = blockIdx.x;
    if (bid < BBLK) role_bucket(smem, ei, gcur, epairs, bid);
    else            role_gbound(batch, gstart, bid - BBLK);
}

// ================================================================ K2: CSR build + proj_in (overlapped)
// blocks [0,NBKT): csr (needs K1's epairs/gcur); [NBKT,NBKT+782): proj (needs only x).
// proj fills the CUs csr's tiny grid (196 blocks) leaves idle.
#define S_X2 132              // fp16 x-tile stride (264B row: 8B-aligned, 2-way-free banks)
#define CP_SMEM_BYTES 33280   // max(csr 22560, proj 16896+16384)

__device__ __forceinline__ void role_csr(char* smem, const int* __restrict__ gcur,
                                         const unsigned int* __restrict__ epairs,
                                         int* __restrict__ rowptr,
                                         unsigned short* __restrict__ srclist, int b) {
    int* lhist = (int*)smem;            // 256
    int* lcur  = lhist + 256;           // 256
    int* pws   = lcur + 256;            // 4
    int* wtot  = pws + 4;               // 4
    int* lsrc  = wtot + 4;              // BSTRIDE
    const int t = threadIdx.x;
    const int lane = t & 63, wv = t >> 6;

    int po = 0;
    for (int j = t; j < b; j += 256) po += gcur[j];
#pragma unroll
    for (int m = 32; m; m >>= 1) po += __shfl_xor(po, m, 64);
    if (lane == 0) pws[wv] = po;
    lhist[t] = 0;
    __syncthreads();
    const int base = pws[0] + pws[1] + pws[2] + pws[3];
    const int cnt = gcur[b];

    for (int i = t; i < cnt; i += 256)
        atomicAdd(&lhist[(epairs[b * BSTRIDE + i] >> 16) & 255], 1);
    __syncthreads();

    const int d = lhist[t];
    int incl = d;
#pragma unroll
    for (int off = 1; off < 64; off <<= 1) {
        const int u = __shfl_up(incl, off, 64);
        if (lane >= off) incl += u;
    }
    if (lane == 63) wtot[wv] = incl;
    __syncthreads();
    int woff = 0;
#pragma unroll
    for (int i = 0; i < 4; ++i) woff += (i < wv) ? wtot[i] : 0;
    const int excl = woff + incl - d;
    lcur[t] = excl;
    const int node = b * 256 + t;
    if (node < N_NODES) rowptr[node] = base + excl;
    if (b == NBKT - 1 && t == 0) rowptr[N_NODES] = base + cnt;  // == N_EDGES
    __syncthreads();

    for (int i = t; i < cnt; i += 256) {
        const unsigned int u = epairs[b * BSTRIDE + i];
        const int pos = atomicAdd(&lcur[(u >> 16) & 255], 1);
        lsrc[pos] = (int)(u & 0xFFFFu);
    }
    __syncthreads();
    for (int i = t; i < cnt; i += 256)
        srclist[base + i] = (unsigned short)lsrc[i];
}

__device__ __forceinline__ void role_proj(char* smem, const float* __restrict__ x,
                                          const float* __restrict__ W,
                                          const float* __restrict__ b,
                                          unsigned char* __restrict__ h8, int bid) {
    __half* A = (__half*)smem;                    // 64*132 halves = 16896 B
    float* Wl = (float*)(smem + 64 * S_X2 * 2);   // 64*64 floats = 16384 B
    const int t = threadIdx.x;
    const int nb = bid * 64;
    for (int i = t; i < 64 * HID; i += 256) Wl[i] = W[i];   // k = 0..63
    // stage x tile as fp16 (output is fp8 anyway; fp16 error negligible)
    for (int i = t; i < 64 * (IN_DIM / 4); i += 256) {
        const int n = i >> 5;
        const int k4 = (i & 31) * 4;
        float4 val = make_float4(0.f, 0.f, 0.f, 0.f);
        if (nb + n < N_NODES)
            val = *(const float4*)(x + (size_t)(nb + n) * IN_DIM + k4);
        union { uint2 u; __half2 h[2]; } pk;
        pk.h[0] = __floats2half2_rn(val.x, val.y);
        pk.h[1] = __floats2half2_rn(val.z, val.w);
        *(uint2*)&A[n * S_X2 + k4] = pk.u;        // 8B-aligned (264n + 8m)
    }
    __syncthreads();

    const int ln = t & 31;
    const int c0 = (t >> 5) * 8;
    float acc[2][8];
#pragma unroll
    for (int j = 0; j < 2; ++j)
#pragma unroll
        for (int c = 0; c < 8; ++c) acc[j][c] = b[c0 + c];
    for (int k = 0; k < 64; ++k) {
        const float a0 = __half2float(A[ln * S_X2 + k]);
        const float a1 = __half2float(A[(ln + 32) * S_X2 + k]);
        const float4 wA = *(const float4*)&Wl[k * HID + c0];
        const float4 wB = *(const float4*)&Wl[k * HID + c0 + 4];
        const float w[8] = {wA.x, wA.y, wA.z, wA.w, wB.x, wB.y, wB.z, wB.w};
#pragma unroll
        for (int c = 0; c < 8; ++c) {
            acc[0][c] = fmaf(a0, w[c], acc[0][c]);
            acc[1][c] = fmaf(a1, w[c], acc[1][c]);
        }
    }
    __syncthreads();                                        // Wl half-1 reads done
    for (int i = t; i < 64 * HID; i += 256) Wl[i] = W[64 * HID + i];  // k = 64..127
    __syncthreads();
    for (int k = 64; k < 128; ++k) {
        const float a0 = __half2float(A[ln * S_X2 + k]);
        const float a1 = __half2float(A[(ln + 32) * S_X2 + k]);
        const float4 wA = *(const float4*)&Wl[(k - 64) * HID + c0];
        const float4 wB = *(const float4*)&Wl[(k - 64) * HID + c0 + 4];
        const float w[8] = {wA.x, wA.y, wA.z, wA.w, wB.x, wB.y, wB.z, wB.w};
#pragma unroll
        for (int c = 0; c < 8; ++c) {
            acc[0][c] = fmaf(a0, w[c], acc[0][c]);
            acc[1][c] = fmaf(a1, w[c], acc[1][c]);
        }
    }
#pragma unroll
    for (int j = 0; j < 2; ++j) {
        const int n = nb + ln + 32 * j;
        if (n < N_NODES) {
            const uint2 p = pack_fp8x8(acc[j]);
            *(uint2*)(h8 + (size_t)n * HID + c0) = p;   // 8B store, c0 mult of 8
        }
    }
}

__global__ __launch_bounds__(256) void k_cp(
        const int* __restrict__ gcur, const unsigned int* __restrict__ epairs,
        const float* __restrict__ x, const float* __restrict__ W,
        const float* __restrict__ b,
        int* __restrict__ rowptr, unsigned short* __restrict__ srcl,
        unsigned char* __restrict__ h8) {
    __shared__ __attribute__((aligned(16))) char smem[CP_SMEM_BYTES];
    const int bid = blockIdx.x;
    if (bid < NBKT) role_csr(smem, gcur, epairs, rowptr, srcl, bid);
    else            role_proj(smem, x, W, b, h8, bid - NBKT);
}

// ---------------------------------------------------------------- fused conv: gather + 2-layer MLP (R16-proven)
#define S_A 65
__global__ __launch_bounds__(256, 4) void k_conv(
        const unsigned char* __restrict__ hin8,
        const int* __restrict__ rowptr, const unsigned short* __restrict__ srclist,
        const float* __restrict__ W1, const float* __restrict__ b1,
        const float* __restrict__ W2, const float* __restrict__ b2,
        unsigned char* __restrict__ hout8) {
    __shared__ float A[64 * S_A];      // 16.6 KB (v, then u)
    __shared__ float Wl[HID * HID];    // 16 KB (W1, then W2)
    const int t = threadIdx.x;
    for (int i = t; i < HID * HID; i += 256) Wl[i] = W1[i];

    const int nb = blockIdx.x * 64;
    const int grp = t >> 3;            // 0..31: node within pass
    const int q = t & 7;               // 8-byte chunk of the 64B row
#pragma unroll
    for (int pass = 0; pass < 2; ++pass) {
        const int nloc = pass * 32 + grp;
        const int node = nb + nloc;
        float acc[8] = {0.f, 0.f, 0.f, 0.f, 0.f, 0.f, 0.f, 0.f};
        if (node < N_NODES) {
            acc_fp8x8(acc, *(const uint2*)(hin8 + (size_t)node * HID + q * 8)); // self
            const int beg = rowptr[node];
            const int end = rowptr[node + 1];
            int e = beg;
            for (; e + 8 <= end; e += 8) {
                int s[8];
#pragma unroll
                for (int i = 0; i < 8; ++i) s[i] = srclist[e + i];
                uint2 r[8];
#pragma unroll
                for (int i = 0; i < 8; ++i)
                    r[i] = *(const uint2*)(hin8 + (size_t)s[i] * HID + q * 8);
#pragma unroll
                for (int i = 0; i < 8; ++i) acc_fp8x8(acc, r[i]);
            }
            for (; e < end; ++e)
                acc_fp8x8(acc, *(const uint2*)(hin8 + (size_t)srclist[e] * HID + q * 8));
        }
        float* dst = &A[nloc * S_A + q * 8];
#pragma unroll
        for (int i = 0; i < 8; ++i) dst[i] = acc[i];
    }
    __syncthreads();

    const int ln = t & 31;
    const int c0 = (t >> 5) * 8;
    float bb[8];
#pragma unroll
    for (int c = 0; c < 8; ++c) bb[c] = b1[c0 + c];

    float acc2[2][8];
    // ---- layer 1
#pragma unroll
    for (int j = 0; j < 2; ++j)
#pragma unroll
        for (int c = 0; c < 8; ++c) acc2[j][c] = bb[c];
    for (int k = 0; k < HID; ++k) {
        const float a0 = A[ln * S_A + k];
        const float a1 = A[(ln + 32) * S_A + k];
        const float4 wA = *(const float4*)&Wl[k * HID + c0];
        const float4 wB = *(const float4*)&Wl[k * HID + c0 + 4];
        const float w[8] = {wA.x, wA.y, wA.z, wA.w, wB.x, wB.y, wB.z, wB.w};
#pragma unroll
        for (int c = 0; c < 8; ++c) {
            acc2[0][c] = fmaf(a0, w[c], acc2[0][c]);
            acc2[1][c] = fmaf(a1, w[c], acc2[1][c]);
        }
    }
    __syncthreads();   // all layer-1 A and Wl reads complete
    // write u = relu(acc2) into A; stage W2 into Wl
#pragma unroll
    for (int j = 0; j < 2; ++j) {
        float* dst = &A[(ln + 32 * j) * S_A + c0];
#pragma unroll
        for (int c = 0; c < 8; ++c) dst[c] = fmaxf(acc2[j][c], 0.0f);
    }
    for (int i = t; i < HID * HID; i += 256) Wl[i] = W2[i];
#pragma unroll
    for (int c = 0; c < 8; ++c) bb[c] = b2[c0 + c];
    __syncthreads();

    // ---- layer 2
#pragma unroll
    for (int j = 0; j < 2; ++j)
#pragma unroll
        for (int c = 0; c < 8; ++c) acc2[j][c] = bb[c];
    for (int k = 0; k < HID; ++k) {
        const float a0 = A[ln * S_A + k];
        const float a1 = A[(ln + 32) * S_A + k];
        const float4 wA = *(const float4*)&Wl[k * HID + c0];
        const float4 wB = *(const float4*)&Wl[k * HID + c0 + 4];
        const float w[8] = {wA.x, wA.y, wA.z, wA.w, wB.x, wB.y, wB.z, wB.w};
#pragma unroll
        for (int c = 0; c < 8; ++c) {
            acc2[0][c] = fmaf(a0, w[c], acc2[0][c]);
            acc2[1][c] = fmaf(a1, w[c], acc2[1][c]);
        }
    }
#pragma unroll
    for (int j = 0; j < 2; ++j) {
        const int n = nb + ln + 32 * j;
        if (n < N_NODES) {
            float f[8];
#pragma unroll
            for (int c = 0; c < 8; ++c) f[c] = fmaxf(acc2[j][c], 0.0f);
            const uint2 p = pack_fp8x8(f);
            *(uint2*)(hout8 + (size_t)n * HID + c0) = p;
        }
    }
}

// ---------------------------------------------------------------- fused mean-pool + proj_out (fp8 read)
__global__ __launch_bounds__(256) void k_poolout(
        const unsigned char* __restrict__ hin8, const int* __restrict__ gstart,
        const float* __restrict__ Wo, const float* __restrict__ bo,
        float* __restrict__ out) {
    __shared__ float Wl[HID * OUT_DIM];   // 32 KB
    __shared__ float red[4][HID];
    __shared__ float mean[HID];
    const int g = blockIdx.x;
    const int t = threadIdx.x;
    for (int i = t; i < HID * OUT_DIM; i += 256) Wl[i] = Wo[i];
    const int c = t & 63;
    const int wv = t >> 6;
    const int beg = gstart[g], end = gstart[g + 1];
    float acc = 0.0f;
    for (int n = beg + wv; n < end; n += 4)
        acc += __builtin_amdgcn_cvt_f32_fp8((int)hin8[(size_t)n * HID + c], 0);
    red[wv][c] = acc;
    __syncthreads();
    if (t < HID) {
        const float cnt = (float)(end - beg);
        mean[t] = cnt > 0.0f ? (red[0][t] + red[1][t] + red[2][t] + red[3][t]) / cnt
                             : 0.0f;
    }
    __syncthreads();
    if (t < OUT_DIM) {
        float o = 0.0f;
        for (int k = 0; k < HID; ++k)
            o = fmaf(mean[k], Wl[k * OUT_DIM + t], o);
        out[g * OUT_DIM + t] = (end > beg) ? o + bo[t] : 0.0f;
    }
}

// ---------------------------------------------------------------- launch
extern "C" void kernel_launch(void* const* d_in, const int* in_sizes, int n_in,
                              void* d_out, int out_size, void* d_ws, size_t ws_size,
                              hipStream_t stream) {
    const float* x     = (const float*)d_in[0];
    const int*   ei    = (const int*)d_in[1];
    const int*   batch = (const int*)d_in[2];
    const float* W_in  = (const float*)d_in[3];
    const float* b_in  = (const float*)d_in[4];
    const float* W1_0  = (const float*)d_in[5];
    const float* b1_0  = (const float*)d_in[6];
    const float* W2_0  = (const float*)d_in[7];
    const float* b2_0  = (const float*)d_in[8];
    const float* W1_1  = (const float*)d_in[9];
    const float* b1_1  = (const float*)d_in[10];
    const float* W2_1  = (const float*)d_in[11];
    const float* b2_1  = (const float*)d_in[12];
    const float* W_out = (const float*)d_in[13];
    const float* b_out = (const float*)d_in[14];
    float* out = (float*)d_out;

    unsigned int*   wsw    = (unsigned int*)d_ws;
    int*            gcur   = (int*)(wsw + OFF_GCUR);
    int*            gstart = (int*)(wsw + OFF_GSTART);
    int*            rowptr = (int*)(wsw + OFF_ROWPTR);
    unsigned short* srcl   = (unsigned short*)(wsw + OFF_SRCL);
    unsigned int*   epairs = (unsigned int*)(wsw + OFF_EPAIRS);
    unsigned char*  hA     = (unsigned char*)(wsw + OFF_HA);
    unsigned char*  hB     = (unsigned char*)(wsw + OFF_HB);

    const int pi_blocks = (N_NODES + 63) / 64;            // 782
    const int cv_blocks = (N_NODES + 63) / 64;            // 782
    const int bg_blocks = BBLK + NBKT;                    // 980
    const int cp_blocks = NBKT + pi_blocks;               // 978

    hipMemsetAsync(gcur, 0, NBKT * sizeof(int), stream);  // graph-capturable
    k_bg<<<bg_blocks, 256, 0, stream>>>(ei, batch, gcur, epairs, gstart);
    k_cp<<<cp_blocks, 256, 0, stream>>>(gcur, epairs, x, W_in, b_in,
                                        rowptr, srcl, hA);
    k_conv<<<cv_blocks, 256, 0, stream>>>(hA, rowptr, srcl, W1_0, b1_0, W2_0, b2_0, hB);
    k_conv<<<cv_blocks, 256, 0, stream>>>(hB, rowptr, srcl, W1_1, b1_1, W2_1, b2_1, hA);
    k_poolout<<<N_GRAPHS, 256, 0, stream>>>(hA, gstart, W_out, b_out, out);
}